// Round 10
// baseline (274.003 us; speedup 1.0000x reference)
//
#include <hip/hip_runtime.h>
#include <hip/hip_fp16.h>

typedef float f32x4 __attribute__((ext_vector_type(4)));
typedef __bf16 bf16x8 __attribute__((ext_vector_type(8)));

#define BB_ 8
#define TT_ 4096
#define DD_ 1024
#define MM_ (BB_*TT_)   // 32768
#define KK_ DD_         // 1024

#define NCH 64
#define LCH (TT_/NCH)   // 64

static __device__ __forceinline__ unsigned short f2bf_rn(float f) {
  unsigned int u = __float_as_uint(f);
  u += 0x7FFFu + ((u >> 16) & 1u);
  return (unsigned short)(u >> 16);
}

// ---------------- conversion: f32 -> bf16 bits (vectorized) ----------------
__global__ void cvt_f32_bf16(const float4* __restrict__ src,
                             ushort4* __restrict__ dst, int n4) {
  int stride = gridDim.x * blockDim.x;
  for (int i = blockIdx.x * blockDim.x + threadIdx.x; i < n4; i += stride) {
    float4 v = src[i];
    ushort4 o;
    o.x = f2bf_rn(v.x); o.y = f2bf_rn(v.y);
    o.z = f2bf_rn(v.z); o.w = f2bf_rn(v.w);
    dst[i] = o;
  }
}

// W interleave: Wcat row e = (D>>5)*64 + mtx*32 + (D&31).  Within each
// 64-col tile: cols 0..31 = Wz rows for 32 channels, cols 32..63 = Wh same
// channels -> a wave's j and j+2 fragments give (k, th) for the SAME channel.
__global__ void cvt_w(const float4* __restrict__ Wz4,
                      const float4* __restrict__ Wh4,
                      ushort4* __restrict__ Wcat) {
  int flat = blockIdx.x * 256 + threadIdx.x;     // 0..524287
  int mtx = flat >> 18;                          // 0 = Wz, 1 = Wh
  int j = flat & 262143;
  float4 v = (mtx ? Wh4 : Wz4)[j];
  int D = j >> 8;                                // source row 0..1023
  int kq = j & 255;                              // float4 col
  int e = ((D >> 5) << 6) + (mtx << 5) + (D & 31);
  ushort4 o;
  o.x = f2bf_rn(v.x); o.y = f2bf_rn(v.y);
  o.z = f2bf_rn(v.z); o.w = f2bf_rn(v.w);
  Wcat[(size_t)e * 256 + kq] = o;
}

// ------ GEMM: 128x256 tile, BK=32, 4 waves, 2 blocks/CU co-resident -------
__device__ __forceinline__ void gload_lds16(const void* g, void* l) {
  __builtin_amdgcn_global_load_lds(
      (const __attribute__((address_space(1))) void*)g,
      (__attribute__((address_space(3))) void*)l, 16, 0, 0);
}

// Buffer (24KB): A [128 rows][32 halfs] @0, B [256 rows][32 halfs] @8192.
// Rounds of 4KB (256 thr x 16B), 64 rows each. Source pre-swizzled: LDS
// chunk-slot s of row r holds global 16B-chunk s ^ (r&3)  [rule #21].
#define STA(q, nb_, kkh) gload_lds16(pXa + (q) * 65536 + (kkh), (nb_) + (q) * 4096 + wofs)
#define STB(q, nb_, kkh) gload_lds16(pWb + (q) * 65536 + (kkh), (nb_) + 8192 + (q) * 4096 + wofs)

// One phase (mh = M-half of the wave's 128 rows). B-frags read at mh==0,
// held in regs across ph1.  R4 barrier skeleton.
#define PH(cb_, mh, STAGEOPS, WAITOPS) do {                                 \
    const char* Ab_ = (const char*)(cb_);                                   \
    bf16x8 af_[4];                                                          \
    _Pragma("unroll")                                                       \
    for (int ii = 0; ii < 4; ++ii)                                          \
      af_[ii] = *reinterpret_cast<const bf16x8*>(                           \
          Ab_ + rAb + (mh) * 4096 + ii * 1024);                             \
    if ((mh) == 0) {                                                        \
      _Pragma("unroll")                                                     \
      for (int j = 0; j < 4; ++j)                                           \
        bfv[j] = *reinterpret_cast<const bf16x8*>(Ab_ + rBb + j * 1024);    \
    }                                                                       \
    STAGEOPS;                                                               \
    WAITOPS;                                                                \
    __builtin_amdgcn_s_barrier();                                           \
    asm volatile("s_waitcnt lgkmcnt(0)" ::: "memory");                      \
    __builtin_amdgcn_sched_barrier(0);                                      \
    __builtin_amdgcn_s_setprio(1);                                          \
    _Pragma("unroll")                                                       \
    for (int ii = 0; ii < 4; ++ii)                                          \
      _Pragma("unroll")                                                     \
      for (int j = 0; j < 4; ++j)                                           \
        acc[(mh) * 4 + ii][j] = __builtin_amdgcn_mfma_f32_16x16x32_bf16(    \
            af_[ii], bfv[j], acc[(mh) * 4 + ii][j], 0, 0, 0);               \
    __builtin_amdgcn_s_setprio(0);                                          \
    asm volatile("" ::: "memory");                                          \
    __builtin_amdgcn_s_barrier();                                           \
  } while (0)

#define VMW(n) asm volatile("s_waitcnt vmcnt(" #n ")" ::: "memory")

__global__ __launch_bounds__(256, 2) void gemm_fused(
    const unsigned short* __restrict__ Xb,   // [M][K] bf16 bits
    const unsigned short* __restrict__ Wb,   // [2048][K] bf16 bits (Wcat)
    const float* __restrict__ bz, const float* __restrict__ bh,
    unsigned int* __restrict__ ZG,           // [M][1024] packed (z | g<<16)
    float* __restrict__ Pp, float* __restrict__ Qq)   // [B][64][1024]
{
  extern __shared__ __align__(16) char smem[];   // 2 x 24KB buffers
  const int tid  = threadIdx.x;
  const int wave = tid >> 6;                     // 0..3 = N quarter
  const int lane = tid & 63;
  const int wn = wave;
  const int fr = lane & 15, kg = lane >> 4;

  // XCD-bijective swizzle (2048 % 8 == 0); N-fastest within each XCD strip.
  int swz = (blockIdx.x & 7) * 256 + (blockIdx.x >> 3);
  const int m0 = (swz >> 3) * 128;               // 256 M-tiles
  const int e0 = (swz & 7) * 256;                // 8 N-tiles (Wcat cols)

  // staging per-thread constants (pre-swizzled global source)
  const int rr = tid >> 2;                           // 0..63 row within round
  const int ac = ((tid & 3) ^ (rr & 3)) * 8;         // swizzled chunk, halfs
  const unsigned short* pXa = Xb + (size_t)(m0 + rr) * KK_ + ac;
  const unsigned short* pWb = Wb + (size_t)(e0 + rr) * KK_ + ac;
  const int wofs = wave * 1024;                      // wave slice (bytes)

  // ds_read per-lane constants (swizzled read side); row&3 == fr&3 always
  const int cksw = ((kg ^ (fr & 3)) << 4);           // chunk byte in 64B row
  const int rAb = fr * 64 + cksw;                    // A base byte (row = ii*16+fr)
  const int rBb = 8192 + (wn * 64 + fr) * 64 + cksw; // B base byte

  f32x4 acc[8][4];
  #pragma unroll
  for (int i = 0; i < 8; i++)
    #pragma unroll
    for (int j = 0; j < 4; j++)
      acc[i][j] = (f32x4){0.f, 0.f, 0.f, 0.f};
  bf16x8 bfv[4];

  // prologue: stage K-tile 0 into buf0 (A: 2 rounds, B: 4 rounds)
  STA(0, smem, 0); STA(1, smem, 0);
  STB(0, smem, 0); STB(1, smem, 0); STB(2, smem, 0); STB(3, smem, 0);
  VMW(0);
  __builtin_amdgcn_s_barrier();

  // main loop: 32 K-tiles; during tile t stage t+1 into the other buffer.
  #pragma unroll 1
  for (int t = 0; t < 31; ++t) {
    const char* cb = smem + (t & 1) * 24576;
    char* nb = smem + ((t + 1) & 1) * 24576;
    const int kn = (t + 1) * 32;                     // half-elem K offset
    // ph0: frags A-mh0 + B; stage all 6 rounds of t+1
    PH(cb, 0, {STA(0, nb, kn); STA(1, nb, kn);
               STB(0, nb, kn); STB(1, nb, kn);
               STB(2, nb, kn); STB(3, nb, kn);}, );
    // ph1: frags A-mh1; drain t+1's loads (issued 2 phases back)
    PH(cb, 1, {}, VMW(0));
  }
  {                                                  // peeled tile 31
    const char* cb = smem + 24576;
    PH(cb, 0, {}, );
    PH(cb, 1, {}, );
  }
  // trailing barrier of last PH: all LDS reads done -> smem reusable

  // ===== epilogue: activation + in-register chunk scan + packed ZG ========
  // lane's channel (j = 0,1): d = dw0 + j*16 + fr ; k = acc[ii][j], th = acc[ii][j+2]
  const int dw0 = (swz & 7) * 128 + wn * 32;         // wave's 32 channels
  const int t0 = m0 & 4095;                          // t base within batch
  const int bidx = m0 >> 12;                         // batch

  float bzv[2], bhv[2];
  #pragma unroll
  for (int j = 0; j < 2; ++j) {
    bzv[j] = bz[dw0 + j * 16 + fr];
    bhv[j] = bh[dw0 + j * 16 + fr];
  }

  unsigned int* ew = (unsigned int*)(smem + wave * 4608);  // [32 t][36 dw]
  const int sub = lane & 7, rowr = lane >> 3;

  float PP[2], QQ[2];
  #pragma unroll
  for (int pass = 0; pass < 4; ++pass) {             // 32 t-rows per pass
    if ((pass & 1) == 0) { PP[0] = PP[1] = 1.f; QQ[0] = QQ[1] = 0.f; }
    #pragma unroll
    for (int iil = 0; iil < 2; ++iil) {              // ii = pass*2 + iil
      const int ii = pass * 2 + iil;
      #pragma unroll
      for (int j = 0; j < 2; ++j) {
        float segP = 1.f, segQ = 0.f;
        #pragma unroll
        for (int r = 0; r < 4; ++r) {                // 4 consecutive t
          float kz = acc[ii][j][r] + bzv[j];
          float th = acc[ii][j + 2][r] + bhv[j];
          float z = 1.0f / (1.0f + __expf(-kz));
          float g = (th >= 0.0f) ? (th + 0.5f)
                                 : (1.0f / (1.0f + __expf(-th)));
          unsigned int pk =
              (unsigned int)__half_as_ushort(__float2half(z)) |
              ((unsigned int)__half_as_ushort(__float2half(g)) << 16);
          ew[(iil * 16 + kg * 4 + r) * 36 + j * 16 + fr] = pk;
          float aa = 1.f - z;
          segP *= aa;
          segQ = fmaf(aa, segQ, z * g);
        }
        // suffix-combine across kg (t-ordered: kg ascending = later)
        float p1 = __shfl_down(segP, 16), q1 = __shfl_down(segQ, 16);
        segQ = fmaf(p1, segQ, q1); segP *= p1;
        float p2 = __shfl_down(segP, 32), q2 = __shfl_down(segQ, 32);
        segQ = fmaf(p2, segQ, q2); segP *= p2;
        QQ[j] = fmaf(segP, QQ[j], segQ);
        PP[j] *= segP;
      }
    }
    if ((pass & 1) == 1 && kg == 0) {                // chunk (pass>>1) done
      const int cg = (t0 >> 6) + (pass >> 1);
      #pragma unroll
      for (int j = 0; j < 2; ++j) {
        size_t po = ((size_t)bidx * NCH + cg) * DD_ + dw0 + j * 16 + fr;
        Pp[po] = PP[j];
        Qq[po] = QQ[j];
      }
    }
    // coalesced ZG store via LDS readback (wave-synchronous, own region)
    #pragma unroll
    for (int q = 0; q < 4; ++q) {
      int rl = q * 8 + rowr;
      uint4 v = *reinterpret_cast<const uint4*>(&ew[rl * 36 + sub * 4]);
      size_t rg = (size_t)(m0 + pass * 32 + rl);
      *reinterpret_cast<uint4*>(&ZG[rg * DD_ + dw0 + sub * 4]) = v;
    }
  }
}

// ---------------- scan phase B: exclusive scan over chunks ----------------
__global__ __launch_bounds__(256) void scan_combine(
    const float* __restrict__ P, const float* __restrict__ Q,
    float* __restrict__ H) {
  const int d = blockIdx.x * 256 + threadIdx.x;   // gridDim.x = 4 -> d 0..1023
  const int b = blockIdx.y;
  float h = 0.f;
  for (int c = 0; c < NCH; ++c) {
    size_t o = ((size_t)b * NCH + c) * DD_ + d;
    H[o] = h;
    h = fmaf(P[o], h, Q[o]);
  }
}

// ---------------- scan phase C: apply + write output ----------------
__global__ __launch_bounds__(256) void scan_apply(
    const uint4* __restrict__ ZG, const float4* __restrict__ H,
    float4* __restrict__ out) {
  const int d4 = threadIdx.x;
  const int c  = blockIdx.x;
  const int b  = blockIdx.y;
  float4 h = H[((size_t)b * NCH + c) * (DD_ / 4) + d4];
  size_t base = ((size_t)b * TT_ + (size_t)c * LCH) * (DD_ / 4) + d4;
  for (int t = 0; t < LCH; ++t) {
    uint4 w = ZG[base + (size_t)t * (DD_ / 4)];
    float z, g, a;
    z = __half2float(__ushort_as_half((unsigned short)(w.x & 0xffff)));
    g = __half2float(__ushort_as_half((unsigned short)(w.x >> 16)));
    a = 1.f - z; h.x = fmaf(a, h.x, z * g);
    z = __half2float(__ushort_as_half((unsigned short)(w.y & 0xffff)));
    g = __half2float(__ushort_as_half((unsigned short)(w.y >> 16)));
    a = 1.f - z; h.y = fmaf(a, h.y, z * g);
    z = __half2float(__ushort_as_half((unsigned short)(w.z & 0xffff)));
    g = __half2float(__ushort_as_half((unsigned short)(w.z >> 16)));
    a = 1.f - z; h.z = fmaf(a, h.z, z * g);
    z = __half2float(__ushort_as_half((unsigned short)(w.w & 0xffff)));
    g = __half2float(__ushort_as_half((unsigned short)(w.w >> 16)));
    a = 1.f - z; h.w = fmaf(a, h.w, z * g);
    out[base + (size_t)t * (DD_ / 4)] = h;
  }
}

extern "C" void kernel_launch(void* const* d_in, const int* in_sizes, int n_in,
                              void* d_out, int out_size, void* d_ws, size_t ws_size,
                              hipStream_t stream) {
  const float* X  = (const float*)d_in[0];  // [8,4096,1024]
  const float* Wz = (const float*)d_in[1];  // [1024,1024]
  const float* bz = (const float*)d_in[2];
  const float* Wh = (const float*)d_in[3];
  const float* bh = (const float*)d_in[4];
  float* out = (float*)d_out;

  const size_t szXb = (size_t)MM_ * DD_ * 2;      // 64 MiB  bf16 X
  const size_t szWb = (size_t)2 * DD_ * DD_ * 2;  //  4 MiB  bf16 Wcat
  const size_t szZG = (size_t)MM_ * DD_ * 4;      // 128 MiB packed z,g
  const size_t szPQ = (size_t)BB_ * NCH * DD_ * 4;//  2 MiB  each

  char* ws = (char*)d_ws;
  unsigned short *Xb, *Wb;
  const size_t needA = szXb + szWb + szZG + 3 * szPQ;
  if (ws_size >= needA) {
    Xb = (unsigned short*)ws;              ws += szXb;
    Wb = (unsigned short*)ws;              ws += szWb;
  } else {
    // fallback: stage X/W inside d_out (dead until scan_apply), rest in ws
    Xb = (unsigned short*)d_out;
    Wb = (unsigned short*)((char*)d_out + szXb);
  }
  unsigned int* ZG = (unsigned int*)ws;  ws += szZG;
  float* P = (float*)ws;  ws += szPQ;
  float* Q = (float*)ws;  ws += szPQ;
  float* H = (float*)ws;

  // 1) convert inputs to bf16 (X straight; W interleaved into Wcat)
  cvt_f32_bf16<<<2048, 256, 0, stream>>>((const float4*)X, (ushort4*)Xb,
                                         (int)((size_t)MM_ * DD_ / 4));
  cvt_w<<<2048, 256, 0, stream>>>((const float4*)Wz, (const float4*)Wh,
                                  (ushort4*)Wb);
  // 2) fused GEMM -> packed ZG + per-chunk P,Q  (128x256 tile, 48KB LDS)
  gemm_fused<<<(MM_ / 128) * ((2 * DD_) / 256), 256, 49152, stream>>>(
      Xb, Wb, bz, bh, ZG, P, Q);

  // 3) chunk combine + apply
  scan_combine<<<dim3(4, BB_), 256, 0, stream>>>(P, Q, H);
  scan_apply<<<dim3(NCH, BB_), 256, 0, stream>>>((const uint4*)ZG,
                                                 (const float4*)H, (float4*)out);
}